// Round 2
// 382.296 us; speedup vs baseline: 1.0054x; 1.0054x over previous
//
#include <hip/hip_runtime.h>
#include <cmath>

#define LIF_L 2048
#define LIF_F 256
#define LIF_B 64
#define LIF_BF (LIF_B * LIF_F)
#define TT 64                 // timesteps per tile
#define NTILE (LIF_L / TT)    // 32 tiles
#define STR 65                // padded LDS row stride: bank = (lane + t) % 32 -> 2-way, free

// Producer-consumer: block = 2 waves.
//   wave 0 (compute): sequential LIF scan, lane = chain, LDS+VALU only.
//   wave 1 (memory):  all global<->LDS traffic, coalesced float4, transposed staging.
// Double-buffered LDS; z overwrites the input tile IN-PLACE (s = (z>=0) is derived
// at store time -- bit-exact vs (v_pre>=thr) since fp32 subtraction preserves sign).
// LDS = 2 * 64*65 * 4B = 33,280 B.
__global__ __launch_bounds__(128) void lif_scan_kernel(
    const float* __restrict__ I, const float* __restrict__ raw_tau,
    const float* __restrict__ thr_p, float* __restrict__ out) {
#pragma clang fp contract(off)
  __shared__ float buf[2][64 * STR];

  const int tid = threadIdx.x;
  const int wid = tid >> 6;    // 0 = compute wave, 1 = memory wave
  const int lane = tid & 63;
  const int cbase = blockIdx.x * 64;

  const float4* __restrict__ Ip = (const float4*)I;
  float4* __restrict__ Zp = (float4*)out;
  float4* __restrict__ Sp = (float4*)(out + (size_t)LIF_BF * LIF_L);

  const int q = lane >> 4;   // sub-chain index 0..3 for load/store phases
  const int m = lane & 15;   // float4 index within a chain's 256B tile row

  float alpha = 0.0f, oma = 0.0f, thr = 0.0f;
  float v = 0.0f;
  float4 inbuf[16];          // 64 VGPRs of staged input (memory wave only)

  if (wid == 0) {
    // alpha in double = correctly-rounded fp32 target (matches numpy semantics)
    const int f = (cbase + lane) & (LIF_F - 1);
    const double rt = (double)raw_tau[f];
    const double sp = (rt > 0.0) ? (rt + log1p(exp(-rt))) : log1p(exp(rt));
    alpha = (float)exp(-1.0 / (sp + 1e-4));
    oma = 1.0f - alpha;
    thr = thr_p[0];
  } else {
    // prologue: tile 0 -> regs -> LDS buf[0]; then issue tile-1 loads (in flight)
#pragma unroll
    for (int k = 0; k < 16; ++k)
      inbuf[k] = Ip[(size_t)(cbase + 4 * k + q) * (LIF_L / 4) + m];
#pragma unroll
    for (int k = 0; k < 16; ++k) {
      const int row = 4 * k + q;
      float* p = &buf[0][row * STR + 4 * m];
      p[0] = inbuf[k].x; p[1] = inbuf[k].y; p[2] = inbuf[k].z; p[3] = inbuf[k].w;
    }
#pragma unroll
    for (int k = 0; k < 16; ++k)
      inbuf[k] = Ip[(size_t)(cbase + 4 * k + q) * (LIF_L / 4) + (TT / 4) + m];
  }
  __syncthreads();

  for (int i = 0; i < NTILE; ++i) {
    if (wid == 1) {
      // phase A: store tile i-1 results. buf[(i-1)&1] holds z written by the
      // compute wave last iteration (barrier-separated). s derived from sign(z).
      if (i >= 1) {
        const float* zb = buf[(i - 1) & 1];
#pragma unroll
        for (int k = 0; k < 16; ++k) {
          const int row = 4 * k + q;
          const float* pz = &zb[row * STR + 4 * m];
          float4 zv = {pz[0], pz[1], pz[2], pz[3]};
          float4 sv = {zv.x >= 0.0f ? 1.0f : 0.0f, zv.y >= 0.0f ? 1.0f : 0.0f,
                       zv.z >= 0.0f ? 1.0f : 0.0f, zv.w >= 0.0f ? 1.0f : 0.0f};
          const size_t oidx =
              (size_t)(cbase + row) * (LIF_L / 4) + (size_t)(i - 1) * (TT / 4) + m;
          Zp[oidx] = zv;
          Sp[oidx] = sv;
        }
      }
      // phase B: stage tile i+1 into the buffer just drained above
      // ((i+1)&1 == (i-1)&1). Same-wave DS ops are in-order: reads above have
      // already returned before these writes land.
      if (i + 1 < NTILE) {
#pragma unroll
        for (int k = 0; k < 16; ++k) {
          const int row = 4 * k + q;
          float* p = &buf[(i + 1) & 1][row * STR + 4 * m];
          p[0] = inbuf[k].x; p[1] = inbuf[k].y; p[2] = inbuf[k].z; p[3] = inbuf[k].w;
        }
      }
      // phase C: issue tile i+2 loads (hidden under next iteration's work)
      if (i + 2 < NTILE) {
#pragma unroll
        for (int k = 0; k < 16; ++k)
          inbuf[k] = Ip[(size_t)(cbase + 4 * k + q) * (LIF_L / 4) +
                        (size_t)(i + 2) * (TT / 4) + m];
      }
    } else {
      // compute wave: sequential scan, lane = chain, in-place z over input.
      float* rowv = &buf[i & 1][lane * STR];
#pragma unroll 16
      for (int t = 0; t < TT; ++t) {
        const float in = rowv[t];
        // contraction OFF: mul, mul, add rounded separately (matches numpy)
        const float vpre = alpha * v + oma * in;
        rowv[t] = 15.0f * (vpre - thr);      // z overwrites input slot
        v = (vpre >= thr) ? 0.0f : vpre;     // == v_pre*(1-s) bit-exactly
      }
    }
    __syncthreads();
  }

  // epilogue: store final tile's results
  if (wid == 1) {
    const float* zb = buf[(NTILE - 1) & 1];
#pragma unroll
    for (int k = 0; k < 16; ++k) {
      const int row = 4 * k + q;
      const float* pz = &zb[row * STR + 4 * m];
      float4 zv = {pz[0], pz[1], pz[2], pz[3]};
      float4 sv = {zv.x >= 0.0f ? 1.0f : 0.0f, zv.y >= 0.0f ? 1.0f : 0.0f,
                   zv.z >= 0.0f ? 1.0f : 0.0f, zv.w >= 0.0f ? 1.0f : 0.0f};
      const size_t oidx =
          (size_t)(cbase + row) * (LIF_L / 4) + (size_t)(NTILE - 1) * (TT / 4) + m;
      Zp[oidx] = zv;
      Sp[oidx] = sv;
    }
  }
}

extern "C" void kernel_launch(void* const* d_in, const int* in_sizes, int n_in,
                              void* d_out, int out_size, void* d_ws,
                              size_t ws_size, hipStream_t stream) {
  const float* I = (const float*)d_in[0];
  const float* raw_tau = (const float*)d_in[1];
  const float* thr = (const float*)d_in[2];
  float* out = (float*)d_out;
  dim3 grid(LIF_BF / 64), block(128);
  lif_scan_kernel<<<grid, block, 0, stream>>>(I, raw_tau, thr, out);
}